// Round 5
// baseline (332.968 us; speedup 1.0000x reference)
//
#include <hip/hip_runtime.h>
#include <hip/hip_bf16.h>

#define EPSF 1e-5f

typedef short short8 __attribute__((ext_vector_type(8)));
typedef short short4v __attribute__((ext_vector_type(4)));
typedef float f32x4 __attribute__((ext_vector_type(4)));

__device__ __forceinline__ short f2bf(float x) {
    __hip_bfloat16 h = __float2bfloat16(x);
    return reinterpret_cast<short&>(h);
}
__device__ __forceinline__ float bf2f(short s) {
    __hip_bfloat16 h = reinterpret_cast<__hip_bfloat16&>(s);
    return __bfloat162float(h);
}

// ---------------------------------------------------------------------------
// Kernel 0: pack W [256,768] f32 -> hi/lo bf16 MFMA B-fragment order.
// Wp[((nt*24+kt)*64 + g*16 + l15)*8 + j] = W[16nt+l15][32kt+8g+j]
// ---------------------------------------------------------------------------
__global__ __launch_bounds__(256) void w_pack_kernel(
    const float* __restrict__ W,
    short* __restrict__ Wp_hi,
    short* __restrict__ Wp_lo)
{
    int t = blockIdx.x * 256 + threadIdx.x;   // 0..24575
    int l15 = t & 15;
    int g   = (t >> 4) & 3;
    int kt  = (t >> 6) % 24;
    int nt  = t / 1536;
    const float* src = W + (size_t)(16 * nt + l15) * 768 + 32 * kt + 8 * g;
    short8 h8, l8;
    #pragma unroll
    for (int j = 0; j < 8; ++j) {
        float w = src[j];
        short h = f2bf(w);
        h8[j] = h;
        l8[j] = f2bf(w - bf2f(h));
    }
    *reinterpret_cast<short8*>(Wp_hi + (size_t)t * 8) = h8;
    *reinterpret_cast<short8*>(Wp_lo + (size_t)t * 8) = l8;
}

// ---------------------------------------------------------------------------
// Kernel 1: fused LayerNorm + MFMA projection. 512 threads, grid 288.
// Writes proj [B,576,256] (row-major) AND projT [B,256,576] (transposed).
// ---------------------------------------------------------------------------
__global__ __launch_bounds__(512) void ln_proj_kernel(
    const float* __restrict__ clip,
    const float* __restrict__ gamma,
    const float* __restrict__ beta,
    const short* __restrict__ Wp_hi,
    const short* __restrict__ Wp_lo,
    const float* __restrict__ bias,
    short* __restrict__ proj,
    short* __restrict__ projT)
{
    __shared__ short xh[16][776];
    __shared__ short xl[16][776];
    __shared__ float redA[8][16];
    __shared__ float redB[8][16];
    __shared__ float muS[16], rsS[16];

    const int tid = threadIdx.x;
    const int b  = blockIdx.x / 36;
    const int n0 = (blockIdx.x % 36) * 16;
    const int nl = tid & 15;
    const int cg = tid >> 4;       // 0..31
    const int w  = tid >> 6;       // 0..7
    const int l  = tid & 63;
    const int l15 = l & 15;
    const int g  = l >> 4;

    const float* base = clip + (size_t)b * 768 * 576 + n0 + nl;

    // ---- single global pass + LN stats ----
    float x[24];
    float s1 = 0.f, s2 = 0.f;
    #pragma unroll
    for (int i = 0; i < 24; ++i) {
        x[i] = base[(size_t)(cg + 32 * i) * 576];
        s1 += x[i]; s2 += x[i] * x[i];
    }
    s1 += __shfl_xor(s1, 16); s2 += __shfl_xor(s2, 16);
    s1 += __shfl_xor(s1, 32); s2 += __shfl_xor(s2, 32);
    if (g == 0) { redA[w][l15] = s1; redB[w][l15] = s2; }
    __syncthreads();
    if (tid < 16) {
        float a = 0.f, q = 0.f;
        #pragma unroll
        for (int k = 0; k < 8; ++k) { a += redA[k][tid]; q += redB[k][tid]; }
        float mu = a * (1.f / 768.f);
        float var = q * (1.f / 768.f) - mu * mu;
        muS[tid] = mu; rsS[tid] = rsqrtf(var + EPSF);
    }
    __syncthreads();
    {
        float mu = muS[nl], rsg = rsS[nl];
        #pragma unroll
        for (int i = 0; i < 24; ++i) {
            int c = cg + 32 * i;
            float y = (x[i] - mu) * rsg * gamma[c] + beta[c];
            short hh = f2bf(y);
            xh[nl][c] = hh;
            xl[nl][c] = f2bf(y - bf2f(hh));
        }
    }
    __syncthreads();

    // ---- MFMA: wave w covers d in [32w, 32w+32) ----
    f32x4 acc[2];
    acc[0] = f32x4{0.f,0.f,0.f,0.f};
    acc[1] = f32x4{0.f,0.f,0.f,0.f};
    for (int kt = 0; kt < 24; ++kt) {
        short8 ah = *reinterpret_cast<const short8*>(&xh[l15][32 * kt + 8 * g]);
        short8 al = *reinterpret_cast<const short8*>(&xl[l15][32 * kt + 8 * g]);
        #pragma unroll
        for (int j = 0; j < 2; ++j) {
            int nt = 2 * w + j;
            size_t off = ((size_t)((nt * 24 + kt) * 64 + l)) * 8;
            short8 bh = *reinterpret_cast<const short8*>(Wp_hi + off);
            short8 bl = *reinterpret_cast<const short8*>(Wp_lo + off);
            acc[j] = __builtin_amdgcn_mfma_f32_16x16x32_bf16(ah, bh, acc[j], 0, 0, 0);
            acc[j] = __builtin_amdgcn_mfma_f32_16x16x32_bf16(al, bh, acc[j], 0, 0, 0);
            acc[j] = __builtin_amdgcn_mfma_f32_16x16x32_bf16(ah, bl, acc[j], 0, 0, 0);
        }
    }

    #pragma unroll
    for (int j = 0; j < 2; ++j) {
        int d = 16 * (2 * w + j) + l15;
        float bb = bias[d];
        #pragma unroll
        for (int r = 0; r < 4; ++r) {
            int tok = n0 + 4 * g + r;
            short v = f2bf(acc[j][r] + bb);
            proj[((size_t)b * 576 + tok) * 256 + d] = v;
            projT[((size_t)b * 256 + d) * 576 + tok] = v;
        }
    }
}

// ---------------------------------------------------------------------------
// Kernel 2: MFMA flash attention, wave-level kv-split.
// Grid 256 = 8 b x 32 q-tiles (128 q). 512 thr = 8 waves x 32 q.
// Waves 0-3: kv [0,288); waves 4-7: kv [288,576). Merge via LDS at end.
// ---------------------------------------------------------------------------
__global__ __launch_bounds__(512, 2) void attn_kernel(
    const short* __restrict__ proj,    // [B,576,256] bf16
    const short* __restrict__ projT,   // [B,256,576] bf16
    const float* __restrict__ rs,      // [B,256,4096]
    const float* __restrict__ alpha_p,
    float* __restrict__ out)           // [B,256,4096]
{
    __shared__ __align__(16) char smem[95232];
    // chunk phase: Ks[h] @ h*16896 (32x264), VT[h] @ 33792+h*20480 (256x40),
    //              Ps[w] @ 74752+w*2560 (32x40)
    // merge phase (post-barrier reuse): xch @ 0 (64KB), ml @ 65536 (2KB)

    const int tid = threadIdx.x;
    const int b  = blockIdx.x >> 5;
    const int q0 = (blockIdx.x & 31) << 7;
    const int w   = tid >> 6;
    const int l   = tid & 63;
    const int l15 = l & 15;
    const int g   = l >> 4;
    const int h   = w >> 2;            // kv half
    const int wq  = w & 3;             // q-subtile within block

    short (*Ks)[264] = reinterpret_cast<short(*)[264]>(smem + h * 16896);
    short (*VT)[40]  = reinterpret_cast<short(*)[40]>(smem + 33792 + h * 20480);
    short (*Ps)[40]  = reinterpret_cast<short(*)[40]>(smem + 74752 + w * 2560);

    const short* kbase  = proj  + (size_t)b * 576 * 256;
    const short* ktbase = projT + (size_t)b * 256 * 576;
    const float* rbase  = rs + (size_t)b * 256 * 4096;
    float* obase = out + (size_t)b * 256 * 4096;

    const int qb = q0 + 32 * wq;

    // ---- Q fragments (2 q-subtiles x 8 d-chunks), direct from global ----
    short8 qf[2][8];
    #pragma unroll
    for (int qt = 0; qt < 2; ++qt) {
        int qg = qb + 16 * qt + l15;
        #pragma unroll
        for (int dc = 0; dc < 8; ++dc) {
            short8 v;
            #pragma unroll
            for (int j = 0; j < 8; ++j)
                v[j] = f2bf(rbase[(size_t)(32 * dc + 8 * g + j) * 4096 + qg]);
            qf[qt][dc] = v;
        }
    }

    f32x4 acc[2][16];
    #pragma unroll
    for (int qt = 0; qt < 2; ++qt)
        #pragma unroll
        for (int dt = 0; dt < 16; ++dt)
            acc[qt][dt] = f32x4{0.f, 0.f, 0.f, 0.f};
    float mrun[2] = {-1e30f, -1e30f};
    float lrun[2] = {0.f, 0.f};

    const int t    = tid & 255;        // local index within half-group
    const int srow = t >> 3, scb = t & 7;
    const int vdg  = t >> 2, vkq = t & 3;
    const int kvh  = 288 * h;

    auto STAGE = [&](int c) {
        const short* src = kbase + (size_t)(kvh + 32 * c) * 256;
        #pragma unroll
        for (int j2 = 0; j2 < 4; ++j2)
            *reinterpret_cast<short8*>(&Ks[srow][32 * scb + 8 * j2]) =
                *reinterpret_cast<const short8*>(src + srow * 256 + 32 * scb + 8 * j2);
        #pragma unroll
        for (int i = 0; i < 4; ++i) {
            int d = 64 * i + vdg;
            *reinterpret_cast<short8*>(&VT[d][8 * vkq]) =
                *reinterpret_cast<const short8*>(ktbase + (size_t)d * 576 + kvh + 32 * c + 8 * vkq);
        }
    };

    STAGE(0);
    __syncthreads();

    for (int c = 0; c < 9; ++c) {
        // ---- S^T = K . Q^T ----
        f32x4 s00{0.f,0.f,0.f,0.f}, s01{0.f,0.f,0.f,0.f};
        f32x4 s10{0.f,0.f,0.f,0.f}, s11{0.f,0.f,0.f,0.f};
        __builtin_amdgcn_s_setprio(1);
        #pragma unroll
        for (int dc = 0; dc < 8; ++dc) {
            short8 kf0 = *reinterpret_cast<const short8*>(&Ks[l15][32 * dc + 8 * g]);
            short8 kf1 = *reinterpret_cast<const short8*>(&Ks[16 + l15][32 * dc + 8 * g]);
            s00 = __builtin_amdgcn_mfma_f32_16x16x32_bf16(kf0, qf[0][dc], s00, 0, 0, 0);
            s01 = __builtin_amdgcn_mfma_f32_16x16x32_bf16(kf0, qf[1][dc], s01, 0, 0, 0);
            s10 = __builtin_amdgcn_mfma_f32_16x16x32_bf16(kf1, qf[0][dc], s10, 0, 0, 0);
            s11 = __builtin_amdgcn_mfma_f32_16x16x32_bf16(kf1, qf[1][dc], s11, 0, 0, 0);
        }
        __builtin_amdgcn_s_setprio(0);

        // ---- online softmax per q-subtile (lane holds kv=16kt+4g+r, q=l15) ----
        #pragma unroll
        for (int qt = 0; qt < 2; ++qt) {
            float p[8];
            #pragma unroll
            for (int j = 0; j < 4; ++j) {
                p[j]     = qt ? s01[j] : s00[j];
                p[4 + j] = qt ? s11[j] : s10[j];
            }
            float pm = p[0];
            #pragma unroll
            for (int j = 1; j < 8; ++j) pm = fmaxf(pm, p[j]);
            pm = fmaxf(pm, __shfl_xor(pm, 16));
            pm = fmaxf(pm, __shfl_xor(pm, 32));
            if (!__all(pm - mrun[qt] <= 8.f)) {        // defer-max (T13)
                float mnew = fmaxf(mrun[qt], pm);
                float sc = __expf(mrun[qt] - mnew);
                lrun[qt] *= sc;
                #pragma unroll
                for (int dt = 0; dt < 16; ++dt) {
                    acc[qt][dt][0] *= sc; acc[qt][dt][1] *= sc;
                    acc[qt][dt][2] *= sc; acc[qt][dt][3] *= sc;
                }
                mrun[qt] = mnew;
            }
            float rsum = 0.f;
            #pragma unroll
            for (int j = 0; j < 8; ++j) { p[j] = __expf(p[j] - mrun[qt]); rsum += p[j]; }
            rsum += __shfl_xor(rsum, 16);
            rsum += __shfl_xor(rsum, 32);
            lrun[qt] += rsum;
            short4v p0, p1;
            p0.x = f2bf(p[0]); p0.y = f2bf(p[1]); p0.z = f2bf(p[2]); p0.w = f2bf(p[3]);
            p1.x = f2bf(p[4]); p1.y = f2bf(p[5]); p1.z = f2bf(p[6]); p1.w = f2bf(p[7]);
            *reinterpret_cast<short4v*>(&Ps[16 * qt + l15][4 * g]) = p0;
            *reinterpret_cast<short4v*>(&Ps[16 * qt + l15][16 + 4 * g]) = p1;
        }

        // ---- O^T += V^T . P^T ----
        short8 pf0 = *reinterpret_cast<const short8*>(&Ps[l15][8 * g]);
        short8 pf1 = *reinterpret_cast<const short8*>(&Ps[16 + l15][8 * g]);
        __builtin_amdgcn_s_setprio(1);
        #pragma unroll
        for (int dt = 0; dt < 16; ++dt) {
            short8 vf = *reinterpret_cast<const short8*>(&VT[16 * dt + l15][8 * g]);
            acc[0][dt] = __builtin_amdgcn_mfma_f32_16x16x32_bf16(vf, pf0, acc[0][dt], 0, 0, 0);
            acc[1][dt] = __builtin_amdgcn_mfma_f32_16x16x32_bf16(vf, pf1, acc[1][dt], 0, 0, 0);
        }
        __builtin_amdgcn_s_setprio(0);

        __syncthreads();
        if (c < 8) { STAGE(c + 1); __syncthreads(); }
    }

    // ---- merge kv halves (wave pair w <-> w^4) ----
    float2* ml = reinterpret_cast<float2*>(smem + 65536);
    if (g == 0) {
        ml[((wq * 2 + h) * 2 + 0) * 16 + l15] = float2{mrun[0], lrun[0]};
        ml[((wq * 2 + h) * 2 + 1) * 16 + l15] = float2{mrun[1], lrun[1]};
    }
    __syncthreads();
    float cs[2], co[2], lt[2];
    #pragma unroll
    for (int qt = 0; qt < 2; ++qt) {
        float2 o = ml[((wq * 2 + (1 - h)) * 2 + qt) * 16 + l15];
        float M = fmaxf(mrun[qt], o.x);
        cs[qt] = __expf(mrun[qt] - M);
        co[qt] = __expf(o.x - M);
        lt[qt] = cs[qt] * lrun[qt] + co[qt] * o.y;
    }

    float4* xch = reinterpret_cast<float4*>(smem);
    #pragma unroll
    for (int qt = 0; qt < 2; ++qt) {
        __syncthreads();
        #pragma unroll
        for (int dtL = 0; dtL < 8; ++dtL) {        // send the half we don't keep
            int dt = 8 * (1 - h) + dtL;
            float4 vv;
            vv.x = acc[qt][dt][0]; vv.y = acc[qt][dt][1];
            vv.z = acc[qt][dt][2]; vv.w = acc[qt][dt][3];
            xch[((wq * 2 + h) * 64 + l) * 8 + dtL] = vv;
        }
        __syncthreads();
        #pragma unroll
        for (int dtL = 0; dtL < 8; ++dtL) {        // merge into the half we keep
            int dt = 8 * h + dtL;
            float4 rv = xch[((wq * 2 + (1 - h)) * 64 + l) * 8 + dtL];
            acc[qt][dt][0] = cs[qt] * acc[qt][dt][0] + co[qt] * rv.x;
            acc[qt][dt][1] = cs[qt] * acc[qt][dt][1] + co[qt] * rv.y;
            acc[qt][dt][2] = cs[qt] * acc[qt][dt][2] + co[qt] * rv.z;
            acc[qt][dt][3] = cs[qt] * acc[qt][dt][3] + co[qt] * rv.w;
        }
    }

    // ---- epilogue: each wave writes its kept d-half for its 32 q ----
    float av = alpha_p[0];
    #pragma unroll
    for (int qt = 0; qt < 2; ++qt) {
        float inv = av / lt[qt];
        int qg = qb + 16 * qt + l15;
        #pragma unroll
        for (int dtL = 0; dtL < 8; ++dtL) {
            int dt = 8 * h + dtL;
            #pragma unroll
            for (int r = 0; r < 4; ++r) {
                int d = 16 * dt + 4 * g + r;
                size_t idx = (size_t)d * 4096 + qg;
                obase[idx] = rbase[idx] + acc[qt][dt][r] * inv;
            }
        }
    }
}

// ---------------------------------------------------------------------------
extern "C" void kernel_launch(void* const* d_in, const int* in_sizes, int n_in,
                              void* d_out, int out_size, void* d_ws, size_t ws_size,
                              hipStream_t stream)
{
    const float* clip  = (const float*)d_in[0];
    const float* rsf   = (const float*)d_in[1];
    const float* gamma = (const float*)d_in[2];
    const float* beta  = (const float*)d_in[3];
    const float* W     = (const float*)d_in[4];
    const float* bias  = (const float*)d_in[5];
    const float* alpha = (const float*)d_in[6];
    float* out = (float*)d_out;

    char* ws = (char*)d_ws;
    short* Wp_hi = (short*)ws;                       // 384 KB
    short* Wp_lo = (short*)(ws + 393216);            // 384 KB
    short* proj  = (short*)(ws + 786432);            // 2.36 MB
    short* projT = (short*)(ws + 3145728);           // 2.36 MB

    hipLaunchKernelGGL(w_pack_kernel, dim3(96), dim3(256), 0, stream, W, Wp_hi, Wp_lo);
    hipLaunchKernelGGL(ln_proj_kernel, dim3(288), dim3(512), 0, stream,
                       clip, gamma, beta, Wp_hi, Wp_lo, bias, proj, projT);
    hipLaunchKernelGGL(attn_kernel, dim3(256), dim3(512), 0, stream,
                       proj, projT, rsf, alpha, out);
}

// Round 6
// 85.879 us; speedup vs baseline: 3.8772x; 3.8772x over previous
//
#include <hip/hip_runtime.h>
#include <hip/hip_bf16.h>

#define EPSF 1e-5f

typedef short short8 __attribute__((ext_vector_type(8)));
typedef short short4v __attribute__((ext_vector_type(4)));
typedef float f32x4 __attribute__((ext_vector_type(4)));

__device__ __forceinline__ short f2bf(float x) {
    __hip_bfloat16 h = __float2bfloat16(x);
    return reinterpret_cast<short&>(h);
}
__device__ __forceinline__ float bf2f(short s) {
    __hip_bfloat16 h = reinterpret_cast<__hip_bfloat16&>(s);
    return __bfloat162float(h);
}

// ---------------------------------------------------------------------------
// Kernel 0: pack W [256,768] f32 -> hi/lo bf16 MFMA B-fragment order.
// Wp[((nt*24+kt)*64 + g*16 + l15)*8 + j] = W[16nt+l15][32kt+8g+j]
// ---------------------------------------------------------------------------
__global__ __launch_bounds__(256) void w_pack_kernel(
    const float* __restrict__ W,
    short* __restrict__ Wp_hi,
    short* __restrict__ Wp_lo)
{
    int t = blockIdx.x * 256 + threadIdx.x;   // 0..24575
    int l15 = t & 15;
    int g   = (t >> 4) & 3;
    int kt  = (t >> 6) % 24;
    int nt  = t / 1536;
    const float* src = W + (size_t)(16 * nt + l15) * 768 + 32 * kt + 8 * g;
    short8 h8, l8;
    #pragma unroll
    for (int j = 0; j < 8; ++j) {
        float w = src[j];
        short h = f2bf(w);
        h8[j] = h;
        l8[j] = f2bf(w - bf2f(h));
    }
    *reinterpret_cast<short8*>(Wp_hi + (size_t)t * 8) = h8;
    *reinterpret_cast<short8*>(Wp_lo + (size_t)t * 8) = l8;
}

// ---------------------------------------------------------------------------
// Kernel 1: fused LayerNorm + MFMA projection. 512 threads, grid 288.
// Writes proj [B,576,256] (row-major) AND projT [B,256,576] (transposed).
// ---------------------------------------------------------------------------
__global__ __launch_bounds__(512) void ln_proj_kernel(
    const float* __restrict__ clip,
    const float* __restrict__ gamma,
    const float* __restrict__ beta,
    const short* __restrict__ Wp_hi,
    const short* __restrict__ Wp_lo,
    const float* __restrict__ bias,
    short* __restrict__ proj,
    short* __restrict__ projT)
{
    __shared__ short xh[16][776];
    __shared__ short xl[16][776];
    __shared__ float redA[8][16];
    __shared__ float redB[8][16];
    __shared__ float muS[16], rsS[16];

    const int tid = threadIdx.x;
    const int b  = blockIdx.x / 36;
    const int n0 = (blockIdx.x % 36) * 16;
    const int nl = tid & 15;
    const int cg = tid >> 4;       // 0..31
    const int w  = tid >> 6;       // 0..7
    const int l  = tid & 63;
    const int l15 = l & 15;
    const int g  = l >> 4;

    const float* base = clip + (size_t)b * 768 * 576 + n0 + nl;

    float x[24];
    float s1 = 0.f, s2 = 0.f;
    #pragma unroll
    for (int i = 0; i < 24; ++i) {
        x[i] = base[(size_t)(cg + 32 * i) * 576];
        s1 += x[i]; s2 += x[i] * x[i];
    }
    s1 += __shfl_xor(s1, 16); s2 += __shfl_xor(s2, 16);
    s1 += __shfl_xor(s1, 32); s2 += __shfl_xor(s2, 32);
    if (g == 0) { redA[w][l15] = s1; redB[w][l15] = s2; }
    __syncthreads();
    if (tid < 16) {
        float a = 0.f, q = 0.f;
        #pragma unroll
        for (int k = 0; k < 8; ++k) { a += redA[k][tid]; q += redB[k][tid]; }
        float mu = a * (1.f / 768.f);
        float var = q * (1.f / 768.f) - mu * mu;
        muS[tid] = mu; rsS[tid] = rsqrtf(var + EPSF);
    }
    __syncthreads();
    {
        float mu = muS[nl], rsg = rsS[nl];
        #pragma unroll
        for (int i = 0; i < 24; ++i) {
            int c = cg + 32 * i;
            float y = (x[i] - mu) * rsg * gamma[c] + beta[c];
            short hh = f2bf(y);
            xh[nl][c] = hh;
            xl[nl][c] = f2bf(y - bf2f(hh));
        }
    }
    __syncthreads();

    f32x4 acc[2];
    acc[0] = f32x4{0.f,0.f,0.f,0.f};
    acc[1] = f32x4{0.f,0.f,0.f,0.f};
    for (int kt = 0; kt < 24; ++kt) {
        short8 ah = *reinterpret_cast<const short8*>(&xh[l15][32 * kt + 8 * g]);
        short8 al = *reinterpret_cast<const short8*>(&xl[l15][32 * kt + 8 * g]);
        #pragma unroll
        for (int j = 0; j < 2; ++j) {
            int nt = 2 * w + j;
            size_t off = ((size_t)((nt * 24 + kt) * 64 + l)) * 8;
            short8 bh = *reinterpret_cast<const short8*>(Wp_hi + off);
            short8 bl = *reinterpret_cast<const short8*>(Wp_lo + off);
            acc[j] = __builtin_amdgcn_mfma_f32_16x16x32_bf16(ah, bh, acc[j], 0, 0, 0);
            acc[j] = __builtin_amdgcn_mfma_f32_16x16x32_bf16(al, bh, acc[j], 0, 0, 0);
            acc[j] = __builtin_amdgcn_mfma_f32_16x16x32_bf16(ah, bl, acc[j], 0, 0, 0);
        }
    }

    #pragma unroll
    for (int j = 0; j < 2; ++j) {
        int d = 16 * (2 * w + j) + l15;
        float bb = bias[d];
        #pragma unroll
        for (int r = 0; r < 4; ++r) {
            int tok = n0 + 4 * g + r;
            short v = f2bf(acc[j][r] + bb);
            proj[((size_t)b * 576 + tok) * 256 + d] = v;
            projT[((size_t)b * 256 + d) * 576 + tok] = v;
        }
    }
}

// ---------------------------------------------------------------------------
// Kernel 2: MFMA flash attention, wave-level kv-split.
// Grid 256 = 8 b x 32 q-tiles (128 q). 512 thr = 8 waves x 32 q.
// Waves 0-3: kv [0,288); waves 4-7: kv [288,576). Merge via LDS at end.
// All acc indexing is compile-time (rule #20).
// ---------------------------------------------------------------------------
__global__ __launch_bounds__(512, 2) void attn_kernel(
    const short* __restrict__ proj,    // [B,576,256] bf16
    const short* __restrict__ projT,   // [B,256,576] bf16
    const float* __restrict__ rs,      // [B,256,4096]
    const float* __restrict__ alpha_p,
    float* __restrict__ out)           // [B,256,4096]
{
    __shared__ __align__(16) char smem[95232];
    // chunk phase: Ks[h] @ h*16896 (32x264), VT[h] @ 33792+h*20480 (256x40),
    //              Ps[w] @ 74752+w*2560 (32x40)
    // merge phase (post-barrier reuse): xch @ 0 (64KB), ml @ 65536 (2KB)

    const int tid = threadIdx.x;
    const int b  = blockIdx.x >> 5;
    const int q0 = (blockIdx.x & 31) << 7;
    const int w   = tid >> 6;
    const int l   = tid & 63;
    const int l15 = l & 15;
    const int g   = l >> 4;
    const int h   = w >> 2;            // kv half
    const int wq  = w & 3;             // q-subtile within block

    short (*Ks)[264] = reinterpret_cast<short(*)[264]>(smem + h * 16896);
    short (*VT)[40]  = reinterpret_cast<short(*)[40]>(smem + 33792 + h * 20480);
    short (*Ps)[40]  = reinterpret_cast<short(*)[40]>(smem + 74752 + w * 2560);

    const short* kbase  = proj  + (size_t)b * 576 * 256;
    const short* ktbase = projT + (size_t)b * 256 * 576;
    const float* rbase  = rs + (size_t)b * 256 * 4096;
    float* obase = out + (size_t)b * 256 * 4096;

    const int qb = q0 + 32 * wq;

    // ---- Q fragments (2 q-subtiles x 8 d-chunks), direct from global ----
    short8 qf[2][8];
    #pragma unroll
    for (int qt = 0; qt < 2; ++qt) {
        int qg = qb + 16 * qt + l15;
        #pragma unroll
        for (int dc = 0; dc < 8; ++dc) {
            short8 v;
            #pragma unroll
            for (int j = 0; j < 8; ++j)
                v[j] = f2bf(rbase[(size_t)(32 * dc + 8 * g + j) * 4096 + qg]);
            qf[qt][dc] = v;
        }
    }

    f32x4 acc[2][16];
    #pragma unroll
    for (int qt = 0; qt < 2; ++qt)
        #pragma unroll
        for (int dt = 0; dt < 16; ++dt)
            acc[qt][dt] = f32x4{0.f, 0.f, 0.f, 0.f};
    float mrun[2] = {-1e30f, -1e30f};
    float lrun[2] = {0.f, 0.f};

    const int t    = tid & 255;        // local index within half-group
    const int srow = t >> 3, scb = t & 7;
    const int vdg  = t >> 2, vkq = t & 3;
    const int kvh  = 288 * h;

    auto STAGE = [&](int c) {
        const short* src = kbase + (size_t)(kvh + 32 * c) * 256;
        #pragma unroll
        for (int j2 = 0; j2 < 4; ++j2)
            *reinterpret_cast<short8*>(&Ks[srow][32 * scb + 8 * j2]) =
                *reinterpret_cast<const short8*>(src + srow * 256 + 32 * scb + 8 * j2);
        #pragma unroll
        for (int i = 0; i < 4; ++i) {
            int d = 64 * i + vdg;
            *reinterpret_cast<short8*>(&VT[d][8 * vkq]) =
                *reinterpret_cast<const short8*>(ktbase + (size_t)d * 576 + kvh + 32 * c + 8 * vkq);
        }
    };

    STAGE(0);
    __syncthreads();

    for (int c = 0; c < 9; ++c) {
        // ---- S^T = K . Q^T ----
        f32x4 s00{0.f,0.f,0.f,0.f}, s01{0.f,0.f,0.f,0.f};
        f32x4 s10{0.f,0.f,0.f,0.f}, s11{0.f,0.f,0.f,0.f};
        __builtin_amdgcn_s_setprio(1);
        #pragma unroll
        for (int dc = 0; dc < 8; ++dc) {
            short8 kf0 = *reinterpret_cast<const short8*>(&Ks[l15][32 * dc + 8 * g]);
            short8 kf1 = *reinterpret_cast<const short8*>(&Ks[16 + l15][32 * dc + 8 * g]);
            s00 = __builtin_amdgcn_mfma_f32_16x16x32_bf16(kf0, qf[0][dc], s00, 0, 0, 0);
            s01 = __builtin_amdgcn_mfma_f32_16x16x32_bf16(kf0, qf[1][dc], s01, 0, 0, 0);
            s10 = __builtin_amdgcn_mfma_f32_16x16x32_bf16(kf1, qf[0][dc], s10, 0, 0, 0);
            s11 = __builtin_amdgcn_mfma_f32_16x16x32_bf16(kf1, qf[1][dc], s11, 0, 0, 0);
        }
        __builtin_amdgcn_s_setprio(0);

        // ---- online softmax per q-subtile (lane holds kv=16kt+4g+r, q=l15) ----
        #pragma unroll
        for (int qt = 0; qt < 2; ++qt) {
            float p[8];
            #pragma unroll
            for (int j = 0; j < 4; ++j) {
                p[j]     = qt ? s01[j] : s00[j];
                p[4 + j] = qt ? s11[j] : s10[j];
            }
            float pm = p[0];
            #pragma unroll
            for (int j = 1; j < 8; ++j) pm = fmaxf(pm, p[j]);
            pm = fmaxf(pm, __shfl_xor(pm, 16));
            pm = fmaxf(pm, __shfl_xor(pm, 32));
            if (!__all(pm - mrun[qt] <= 8.f)) {        // defer-max (T13)
                float mnew = fmaxf(mrun[qt], pm);
                float sc = __expf(mrun[qt] - mnew);
                lrun[qt] *= sc;
                #pragma unroll
                for (int dt = 0; dt < 16; ++dt) {
                    acc[qt][dt][0] *= sc; acc[qt][dt][1] *= sc;
                    acc[qt][dt][2] *= sc; acc[qt][dt][3] *= sc;
                }
                mrun[qt] = mnew;
            }
            float rsum = 0.f;
            #pragma unroll
            for (int j = 0; j < 8; ++j) { p[j] = __expf(p[j] - mrun[qt]); rsum += p[j]; }
            rsum += __shfl_xor(rsum, 16);
            rsum += __shfl_xor(rsum, 32);
            lrun[qt] += rsum;
            short4v p0, p1;
            p0.x = f2bf(p[0]); p0.y = f2bf(p[1]); p0.z = f2bf(p[2]); p0.w = f2bf(p[3]);
            p1.x = f2bf(p[4]); p1.y = f2bf(p[5]); p1.z = f2bf(p[6]); p1.w = f2bf(p[7]);
            *reinterpret_cast<short4v*>(&Ps[16 * qt + l15][4 * g]) = p0;
            *reinterpret_cast<short4v*>(&Ps[16 * qt + l15][16 + 4 * g]) = p1;
        }

        // ---- O^T += V^T . P^T ----
        short8 pf0 = *reinterpret_cast<const short8*>(&Ps[l15][8 * g]);
        short8 pf1 = *reinterpret_cast<const short8*>(&Ps[16 + l15][8 * g]);
        __builtin_amdgcn_s_setprio(1);
        #pragma unroll
        for (int dt = 0; dt < 16; ++dt) {
            short8 vf = *reinterpret_cast<const short8*>(&VT[16 * dt + l15][8 * g]);
            acc[0][dt] = __builtin_amdgcn_mfma_f32_16x16x32_bf16(vf, pf0, acc[0][dt], 0, 0, 0);
            acc[1][dt] = __builtin_amdgcn_mfma_f32_16x16x32_bf16(vf, pf1, acc[1][dt], 0, 0, 0);
        }
        __builtin_amdgcn_s_setprio(0);

        __syncthreads();
        if (c < 8) { STAGE(c + 1); __syncthreads(); }
    }

    // ---- merge kv halves (wave pair w <-> w^4); all acc indices static ----
    float2* ml = reinterpret_cast<float2*>(smem + 65536);
    if (g == 0) {
        ml[((wq * 2 + h) * 2 + 0) * 16 + l15] = float2{mrun[0], lrun[0]};
        ml[((wq * 2 + h) * 2 + 1) * 16 + l15] = float2{mrun[1], lrun[1]};
    }
    __syncthreads();
    float cs[2], co[2], lt[2];
    #pragma unroll
    for (int qt = 0; qt < 2; ++qt) {
        float2 o = ml[((wq * 2 + (1 - h)) * 2 + qt) * 16 + l15];
        float M = fmaxf(mrun[qt], o.x);
        cs[qt] = __expf(mrun[qt] - M);
        co[qt] = __expf(o.x - M);
        lt[qt] = cs[qt] * lrun[qt] + co[qt] * o.y;
    }

    float4* xch = reinterpret_cast<float4*>(smem);
    #pragma unroll
    for (int qt = 0; qt < 2; ++qt) {
        __syncthreads();
        if (h == 0) {          // send dt 8..15 (the half we don't keep)
            #pragma unroll
            for (int dtL = 0; dtL < 8; ++dtL) {
                float4 vv;
                vv.x = acc[qt][8 + dtL][0]; vv.y = acc[qt][8 + dtL][1];
                vv.z = acc[qt][8 + dtL][2]; vv.w = acc[qt][8 + dtL][3];
                xch[((wq * 2 + 0) * 64 + l) * 8 + dtL] = vv;
            }
        } else {               // send dt 0..7
            #pragma unroll
            for (int dtL = 0; dtL < 8; ++dtL) {
                float4 vv;
                vv.x = acc[qt][dtL][0]; vv.y = acc[qt][dtL][1];
                vv.z = acc[qt][dtL][2]; vv.w = acc[qt][dtL][3];
                xch[((wq * 2 + 1) * 64 + l) * 8 + dtL] = vv;
            }
        }
        __syncthreads();
        if (h == 0) {          // merge partner's dt 0..7 into kept half
            #pragma unroll
            for (int dtL = 0; dtL < 8; ++dtL) {
                float4 rv = xch[((wq * 2 + 1) * 64 + l) * 8 + dtL];
                acc[qt][dtL][0] = cs[qt] * acc[qt][dtL][0] + co[qt] * rv.x;
                acc[qt][dtL][1] = cs[qt] * acc[qt][dtL][1] + co[qt] * rv.y;
                acc[qt][dtL][2] = cs[qt] * acc[qt][dtL][2] + co[qt] * rv.z;
                acc[qt][dtL][3] = cs[qt] * acc[qt][dtL][3] + co[qt] * rv.w;
            }
        } else {               // merge partner's dt 8..15 into kept half
            #pragma unroll
            for (int dtL = 0; dtL < 8; ++dtL) {
                float4 rv = xch[((wq * 2 + 0) * 64 + l) * 8 + dtL];
                acc[qt][8 + dtL][0] = cs[qt] * acc[qt][8 + dtL][0] + co[qt] * rv.x;
                acc[qt][8 + dtL][1] = cs[qt] * acc[qt][8 + dtL][1] + co[qt] * rv.y;
                acc[qt][8 + dtL][2] = cs[qt] * acc[qt][8 + dtL][2] + co[qt] * rv.z;
                acc[qt][8 + dtL][3] = cs[qt] * acc[qt][8 + dtL][3] + co[qt] * rv.w;
            }
        }
    }

    // ---- epilogue: wave writes its kept d-half for its 32 q (static idx) ----
    float av = alpha_p[0];
    #pragma unroll
    for (int qt = 0; qt < 2; ++qt) {
        float inv = av / lt[qt];
        int qg = qb + 16 * qt + l15;
        if (h == 0) {
            #pragma unroll
            for (int dtL = 0; dtL < 8; ++dtL) {
                #pragma unroll
                for (int r = 0; r < 4; ++r) {
                    int d = 16 * dtL + 4 * g + r;
                    size_t idx = (size_t)d * 4096 + qg;
                    obase[idx] = rbase[idx] + acc[qt][dtL][r] * inv;
                }
            }
        } else {
            #pragma unroll
            for (int dtL = 0; dtL < 8; ++dtL) {
                #pragma unroll
                for (int r = 0; r < 4; ++r) {
                    int d = 16 * (8 + dtL) + 4 * g + r;
                    size_t idx = (size_t)d * 4096 + qg;
                    obase[idx] = rbase[idx] + acc[qt][8 + dtL][r] * inv;
                }
            }
        }
    }
}

// ---------------------------------------------------------------------------
extern "C" void kernel_launch(void* const* d_in, const int* in_sizes, int n_in,
                              void* d_out, int out_size, void* d_ws, size_t ws_size,
                              hipStream_t stream)
{
    const float* clip  = (const float*)d_in[0];
    const float* rsf   = (const float*)d_in[1];
    const float* gamma = (const float*)d_in[2];
    const float* beta  = (const float*)d_in[3];
    const float* W     = (const float*)d_in[4];
    const float* bias  = (const float*)d_in[5];
    const float* alpha = (const float*)d_in[6];
    float* out = (float*)d_out;

    char* ws = (char*)d_ws;
    short* Wp_hi = (short*)ws;                       // 384 KB
    short* Wp_lo = (short*)(ws + 393216);            // 384 KB
    short* proj  = (short*)(ws + 786432);            // 2.36 MB
    short* projT = (short*)(ws + 3145728);           // 2.36 MB

    hipLaunchKernelGGL(w_pack_kernel, dim3(96), dim3(256), 0, stream, W, Wp_hi, Wp_lo);
    hipLaunchKernelGGL(ln_proj_kernel, dim3(288), dim3(512), 0, stream,
                       clip, gamma, beta, Wp_hi, Wp_lo, bias, proj, projT);
    hipLaunchKernelGGL(attn_kernel, dim3(256), dim3(512), 0, stream,
                       proj, projT, rsf, alpha, out);
}